// Round 1
// baseline (386.990 us; speedup 1.0000x reference)
//
#include <hip/hip_runtime.h>
#include <stdint.h>

// Qatten_Weight fused kernel — Round 0 baseline (fp32 vector ALU).
// B=16384 A=8 S=512 U=64 H=4 E=64 HE=256. Only states[:,0,:] is live;
// agent_qs and actions are unused by the reference.
//
// Per block: BT=16 batch rows, 256 threads (4 waves, wave w == head h for
// the GEMM phases).
//   P1: hmid[b,h,f] = relu(st@sel_w1 + b1)   (s-chunked, 17.2 GFLOP total)
//   P2: sel[b,h,e]  = hmid@sel_w2            (bf16 LDS intermediates)
//   P3: m[b,h,u]    = sum_e key_w[h,u,e]*sel[b,h,e]   (re-associated keys)
//   P4: logits[b,h,a] = sum_u st[b,a*64+u]*m[b,h,u];  v-net partial sums
//   P5: softmax/entropy/reg + head_attend + v outputs
// Upgrade path for later rounds: P1 -> bf16 MFMA 16x16x32.

#define BT 16
constexpr int BB = 16384, AA = 8, SS = 512, UU = 64, HH = 4, EE = 64, HE = 256;

__device__ __forceinline__ unsigned short f2bf(float x) {
  union { float f; uint32_t u; } v; v.f = x;
  uint32_t r = v.u + 0x7fffu + ((v.u >> 16) & 1u);   // RNE
  return (unsigned short)(r >> 16);
}
__device__ __forceinline__ float bf_lo(uint32_t p) { return __uint_as_float(p << 16); }
__device__ __forceinline__ float bf_hi(uint32_t p) { return __uint_as_float(p & 0xffff0000u); }

__global__ __launch_bounds__(256) void qatten_fused(
    const float* __restrict__ states,
    const float* __restrict__ sel_w1, const float* __restrict__ sel_b1,
    const float* __restrict__ sel_w2, const float* __restrict__ key_w,
    const float* __restrict__ v_w1,  const float* __restrict__ v_b1,
    const float* __restrict__ v_w2,  const float* __restrict__ v_b2,
    float* __restrict__ out)
{
  __shared__ float          stChunk[BT][132];   //  8448 B, fp32 st s-chunk
  __shared__ unsigned short hmidL[BT][1040];    // 33280 B, bf16 [b][h*260+f]
  __shared__ unsigned short selL[BT][272];      //  8704 B, bf16 [b][h*68+e]
  __shared__ unsigned short mL[BT][272];        //  8704 B, bf16 [b][h*68+u]
  __shared__ float          logitsL[BT][33];    //  2112 B
  __shared__ float          wtsL[BT][33];       //  2112 B   (total 63360 B)

  const int t    = threadIdx.x;
  const int b0   = blockIdx.x * BT;
  const int h    = t >> 6;        // wave id == head id for GEMM phases
  const int lane = t & 63;

  // ---------------- Phase 1: hmid = relu(st @ sel_w1[h] + b1[h]) ----------
  const int f0 = lane << 2;       // 4 consecutive HE-features per thread
  float acc[BT][4];
  {
    float4 bias = *(const float4*)(sel_b1 + h * HE + f0);
    #pragma unroll
    for (int b = 0; b < BT; ++b) {
      acc[b][0] = bias.x; acc[b][1] = bias.y; acc[b][2] = bias.z; acc[b][3] = bias.w;
    }
  }
  for (int c = 0; c < 4; ++c) {
    __syncthreads();              // protect previous chunk's readers
    #pragma unroll
    for (int k = 0; k < 2; ++k) { // 16 rows x 128 floats = 512 float4
      int idx = t + 256 * k;
      int row = idx >> 5, col = (idx & 31) << 2;
      *(float4*)(&stChunk[row][col]) =
          *(const float4*)(states + (size_t)(b0 + row) * (AA * SS) + c * 128 + col);
    }
    __syncthreads();
    const float* w1p = sel_w1 + ((size_t)h * SS + c * 128) * HE + f0;
    #pragma unroll 2
    for (int s = 0; s < 128; s += 4) {
      float4 wa = *(const float4*)(w1p + (size_t)(s + 0) * HE);
      float4 wb = *(const float4*)(w1p + (size_t)(s + 1) * HE);
      float4 wc = *(const float4*)(w1p + (size_t)(s + 2) * HE);
      float4 wd = *(const float4*)(w1p + (size_t)(s + 3) * HE);
      #pragma unroll
      for (int b = 0; b < BT; ++b) {
        float4 sv = *(const float4*)(&stChunk[b][s]);
        acc[b][0] = fmaf(sv.x, wa.x, acc[b][0]);
        acc[b][1] = fmaf(sv.x, wa.y, acc[b][1]);
        acc[b][2] = fmaf(sv.x, wa.z, acc[b][2]);
        acc[b][3] = fmaf(sv.x, wa.w, acc[b][3]);
        acc[b][0] = fmaf(sv.y, wb.x, acc[b][0]);
        acc[b][1] = fmaf(sv.y, wb.y, acc[b][1]);
        acc[b][2] = fmaf(sv.y, wb.z, acc[b][2]);
        acc[b][3] = fmaf(sv.y, wb.w, acc[b][3]);
        acc[b][0] = fmaf(sv.z, wc.x, acc[b][0]);
        acc[b][1] = fmaf(sv.z, wc.y, acc[b][1]);
        acc[b][2] = fmaf(sv.z, wc.z, acc[b][2]);
        acc[b][3] = fmaf(sv.z, wc.w, acc[b][3]);
        acc[b][0] = fmaf(sv.w, wd.x, acc[b][0]);
        acc[b][1] = fmaf(sv.w, wd.y, acc[b][1]);
        acc[b][2] = fmaf(sv.w, wd.z, acc[b][2]);
        acc[b][3] = fmaf(sv.w, wd.w, acc[b][3]);
      }
    }
  }
  #pragma unroll
  for (int b = 0; b < BT; ++b) {
    #pragma unroll
    for (int j = 0; j < 4; ++j)
      hmidL[b][h * 260 + f0 + j] = f2bf(fmaxf(acc[b][j], 0.f));
  }
  __syncthreads();

  // ---------------- Phase 2: sel[b,h,e] = hmid @ sel_w2[h] ----------------
  float acc2[BT];
  #pragma unroll
  for (int b = 0; b < BT; ++b) acc2[b] = 0.f;
  {
    const float* w2p = sel_w2 + (size_t)h * HE * EE + lane;   // e = lane
    #pragma unroll 2
    for (int f = 0; f < HE; f += 2) {
      float va = w2p[(size_t)f * EE];
      float vb = w2p[(size_t)(f + 1) * EE];
      #pragma unroll
      for (int b = 0; b < BT; ++b) {
        uint32_t p = *(const uint32_t*)(&hmidL[b][h * 260 + f]);
        acc2[b] = fmaf(bf_lo(p), va, acc2[b]);
        acc2[b] = fmaf(bf_hi(p), vb, acc2[b]);
      }
    }
  }
  #pragma unroll
  for (int b = 0; b < BT; ++b) selL[b][h * 68 + lane] = f2bf(acc2[b]);
  __syncthreads();

  // ------- Phase 3: m[b,h,u] = sum_e key_w[h,u,e] * sel[b,h,e] ------------
  float acc3[BT];
  #pragma unroll
  for (int b = 0; b < BT; ++b) acc3[b] = 0.f;
  {
    const float* kwp = key_w + ((size_t)h * UU + lane) * EE;  // u = lane
    #pragma unroll 4
    for (int e4 = 0; e4 < EE; e4 += 4) {
      float4 kv = *(const float4*)(kwp + e4);
      #pragma unroll
      for (int b = 0; b < BT; ++b) {
        uint32_t p0 = *(const uint32_t*)(&selL[b][h * 68 + e4]);
        uint32_t p1 = *(const uint32_t*)(&selL[b][h * 68 + e4 + 2]);
        acc3[b] = fmaf(bf_lo(p0), kv.x, acc3[b]);
        acc3[b] = fmaf(bf_hi(p0), kv.y, acc3[b]);
        acc3[b] = fmaf(bf_lo(p1), kv.z, acc3[b]);
        acc3[b] = fmaf(bf_hi(p1), kv.w, acc3[b]);
      }
    }
  }
  #pragma unroll
  for (int b = 0; b < BT; ++b) mL[b][h * 68 + lane] = f2bf(acc3[b]);
  __syncthreads();

  // ---- Phase 4: v-net hidden partials + logits (st re-staged per chunk) ---
  float vacc[4] = {0.f, 0.f, 0.f, 0.f};    // wave wv owns b = 4*wv..4*wv+3
  const int wv = t >> 6;
  for (int c = 0; c < 4; ++c) {
    __syncthreads();
    #pragma unroll
    for (int k = 0; k < 2; ++k) {
      int idx = t + 256 * k;
      int row = idx >> 5, col = (idx & 31) << 2;
      *(float4*)(&stChunk[row][col]) =
          *(const float4*)(states + (size_t)(b0 + row) * (AA * SS) + c * 128 + col);
    }
    __syncthreads();
    const float* vwp = v_w1 + (size_t)(c * 128) * EE + lane;  // e = lane
    #pragma unroll 4
    for (int s = 0; s < 128; s += 4) {
      float w0 = vwp[(size_t)(s + 0) * EE];
      float w1 = vwp[(size_t)(s + 1) * EE];
      float w2 = vwp[(size_t)(s + 2) * EE];
      float w3 = vwp[(size_t)(s + 3) * EE];
      #pragma unroll
      for (int i = 0; i < 4; ++i) {
        float4 sv = *(const float4*)(&stChunk[wv * 4 + i][s]);
        vacc[i] = fmaf(sv.x, w0, vacc[i]);
        vacc[i] = fmaf(sv.y, w1, vacc[i]);
        vacc[i] = fmaf(sv.z, w2, vacc[i]);
        vacc[i] = fmaf(sv.w, w3, vacc[i]);
      }
    }
    // logits for a in {2c, 2c+1}: chunk holds st[b][a*64+u] at [a_local*64+u]
    if (t < 128) {
      int b = t >> 3, r = t & 7;
      int hh = r >> 1, al = r & 1;
      int a = c * 2 + al;
      float lg = 0.f;
      #pragma unroll
      for (int u4 = 0; u4 < 64; u4 += 4) {
        float4 sv = *(const float4*)(&stChunk[b][al * 64 + u4]);
        uint32_t p0 = *(const uint32_t*)(&mL[b][hh * 68 + u4]);
        uint32_t p1 = *(const uint32_t*)(&mL[b][hh * 68 + u4 + 2]);
        lg = fmaf(sv.x, bf_lo(p0), lg);
        lg = fmaf(sv.y, bf_hi(p0), lg);
        lg = fmaf(sv.z, bf_lo(p1), lg);
        lg = fmaf(sv.w, bf_hi(p1), lg);
      }
      logitsL[b][hh * 8 + a] = lg;   // raw (unscaled) logits
    }
  }
  // v finalize: hidden=relu(vacc+b1), y=hidden*v_w2, reduce over e-lanes
  {
    float b1v = v_b1[lane];
    float w2v = v_w2[lane];
    float b2v = v_b2[0];
    #pragma unroll
    for (int i = 0; i < 4; ++i) {
      float y = fmaxf(vacc[i] + b1v, 0.f) * w2v;
      #pragma unroll
      for (int off = 32; off > 0; off >>= 1) y += __shfl_xor(y, off);
      if (lane == 0) out[(size_t)BB * AA + b0 + wv * 4 + i] = y + b2v;
    }
  }
  __syncthreads();

  // ---------------- Phase 5: softmax, entropy, reg, head_attend -----------
  if (t < 64) {                    // wave 0: one (b,h) pair per lane
    int b = t >> 2, hh = t & 3;
    float lg[8], sc[8];
    float regPart = 0.f, mx = -1e30f;
    #pragma unroll
    for (int a = 0; a < 8; ++a) {
      lg[a] = logitsL[b][hh * 8 + a];
      regPart += lg[a] * lg[a];
      sc[a] = lg[a] * 0.125f;      // / sqrt(E)
      mx = fmaxf(mx, sc[a]);
    }
    float sum = 0.f;
    #pragma unroll
    for (int a = 0; a < 8; ++a) { sc[a] = __expf(sc[a] - mx); sum += sc[a]; }
    float inv = 1.f / sum;
    float ent = 0.f;
    #pragma unroll
    for (int a = 0; a < 8; ++a) {
      float w = sc[a] * inv;
      wtsL[b][hh * 8 + a] = w;
      ent += w * __logf(w + 1e-8f);
    }
    // attend_mag_regs: sum over all 64 lanes, one atomic per block
    float rp = regPart;
    #pragma unroll
    for (int off = 32; off > 0; off >>= 1) rp += __shfl_xor(rp, off);
    if (t == 0)
      atomicAdd(out + (size_t)BB * AA + BB, rp * (0.001f / ((float)BB * (float)AA)));
    // head_entropies: reduce over b (lane bits 2..5), lanes 0..3 hold head t
    float ep = ent;
    #pragma unroll
    for (int off = 4; off <= 32; off <<= 1) ep += __shfl_xor(ep, off);
    if (t < 4)
      atomicAdd(out + (size_t)BB * AA + BB + 1 + t, -ep / (float)BB);
  }
  __syncthreads();
  if (t < 128) {                   // head_attend[b][a] = sum_h weights
    int b = t >> 3, a = t & 7;
    float s = wtsL[b][a] + wtsL[b][8 + a] + wtsL[b][16 + a] + wtsL[b][24 + a];
    out[(size_t)(b0 + b) * AA + a] = s;
  }
}

extern "C" void kernel_launch(void* const* d_in, const int* in_sizes, int n_in,
                              void* d_out, int out_size, void* d_ws, size_t ws_size,
                              hipStream_t stream) {
  (void)in_sizes; (void)n_in; (void)d_ws; (void)ws_size; (void)out_size;
  const float* states = (const float*)d_in[1];
  const float* sel_w1 = (const float*)d_in[3];
  const float* sel_b1 = (const float*)d_in[4];
  const float* sel_w2 = (const float*)d_in[5];
  const float* key_w  = (const float*)d_in[6];
  const float* v_w1   = (const float*)d_in[7];
  const float* v_b1   = (const float*)d_in[8];
  const float* v_w2   = (const float*)d_in[9];
  const float* v_b2   = (const float*)d_in[10];
  float* out = (float*)d_out;

  // zero the atomically-accumulated scalar outputs (reg + 4 entropies)
  hipMemsetAsync(out + (size_t)BB * AA + BB, 0, 5 * sizeof(float), stream);

  qatten_fused<<<BB / BT, 256, 0, stream>>>(
      states, sel_w1, sel_b1, sel_w2, key_w, v_w1, v_b1, v_w2, v_b2, out);
}

// Round 2
// 179.664 us; speedup vs baseline: 2.1540x; 2.1540x over previous
//
#include <hip/hip_runtime.h>
#include <stdint.h>

// Qatten_Weight — Round 2: bf16 MFMA (16x16x32) for all GEMM phases.
// B=16384 A=8 S=512 U=64 H=4 E=64 HE=256. Grid 512 x 256thr, BT=32 rows/block.
// Wave w: M-tile = w&1 (16 rows), N-half = w>>1 (waves 0,1 share B-stream -> L1).
// Prep kernel converts weights to bf16 transposed so B-frags are contiguous 16B.

typedef __attribute__((ext_vector_type(8))) short short8v;  // 8 bf16 = 4 VGPR
typedef __attribute__((ext_vector_type(4))) float f32x4;

constexpr int BB = 16384, AA = 8, SS = 512, UU = 64, HH = 4, EE = 64, HE = 256;
constexpr int BT = 32;
constexpr int OUTV = BB * AA, OUTR = OUTV + BB, OUTE = OUTR + 1;

// ws layout (bf16 element offsets)
constexpr int OFF_W1T  = 0;              // sel_w1T [4][256][512]  (h,f,s)
constexpr int OFF_W2T  = 524288;         // sel_w2T [4][64][256]   (h,e,f)
constexpr int OFF_VW1T = 589824;         // v_w1T   [64][512]      (e,s)
constexpr int OFF_KW   = 622592;         // key_wB  [4][64][64]    (h,u,e)
constexpr int PREP_N   = 638976;

__device__ __forceinline__ unsigned short f2bf(float x) {
  union { float f; uint32_t u; } v; v.f = x;
  uint32_t r = v.u + 0x7fffu + ((v.u >> 16) & 1u);   // RNE
  return (unsigned short)(r >> 16);
}
__device__ __forceinline__ float bf2f(short h) {
  union { uint32_t u; float f; } v; v.u = ((uint32_t)(unsigned short)h) << 16;
  return v.f;
}

__global__ __launch_bounds__(256) void prep_kernel(
    const float* __restrict__ sel_w1, const float* __restrict__ sel_w2,
    const float* __restrict__ v_w1,  const float* __restrict__ key_w,
    unsigned short* __restrict__ ws) {
  int idx = blockIdx.x * 256 + threadIdx.x;
  if (idx >= PREP_N) return;
  float val;
  if (idx < OFF_W2T) {                       // [h][f][s] <- sel_w1[h][s][f]
    int i = idx; int s = i & 511, f = (i >> 9) & 255, h = i >> 17;
    val = sel_w1[((h << 9) + s) * 256 + f];
  } else if (idx < OFF_VW1T) {               // [h][e][f] <- sel_w2[h][f][e]
    int i = idx - OFF_W2T; int f = i & 255, e = (i >> 8) & 63, h = i >> 14;
    val = sel_w2[((h << 8) + f) * 64 + e];
  } else if (idx < OFF_KW) {                 // [e][s] <- v_w1[s][e]
    int i = idx - OFF_VW1T; int s = i & 511, e = i >> 9;
    val = v_w1[s * 64 + e];
  } else {                                   // key_w cast, same layout
    val = key_w[idx - OFF_KW];
  }
  ws[idx] = f2bf(val);
}

__global__ __launch_bounds__(256, 2) void qatten_mfma(
    const float* __restrict__ states, const float* __restrict__ sel_b1,
    const float* __restrict__ v_b1,  const float* __restrict__ v_w2,
    const float* __restrict__ v_b2,  const unsigned short* __restrict__ ws,
    float* __restrict__ out) {
  __shared__ __align__(16) unsigned char lds[63232];
  short* hmid = (short*)lds;                 // [32][264] bf16 (per-head)
  short* sel  = (short*)(lds + 16896);       // [32][72]  bf16 (per-head)
  short* stl  = (short*)lds;                 // [32][520] bf16 (P4 alias)
  short* mm   = (short*)(lds + 33280);       // [32][264] bf16 (all heads)
  short* vhid = (short*)(lds + 50176);       // [32][72]  bf16
  float* logitsL = (float*)(lds + 54784);    // [32][33]
  float* wtsL    = (float*)(lds + 59008);    // [32][33]

  const int t  = threadIdx.x;
  const int w  = t >> 6, l = t & 63;
  const int mt = w & 1, nh = w >> 1;         // M-tile, N-half
  const int lr = l & 15, g = l >> 4;
  const int b0 = blockIdx.x * BT;
  const short* w1T  = (const short*)ws + OFF_W1T;
  const short* w2T  = (const short*)ws + OFF_W2T;
  const short* vw1T = (const short*)ws + OFF_VW1T;
  const short* kwB  = (const short*)ws + OFF_KW;

  // ---- A-fragments: 16 rows of st, bf16, kept in registers (64 VGPR) ----
  short8v aF[16];
  {
    const float* srow = states + (size_t)(b0 + mt * 16 + lr) * (AA * SS);
    #pragma unroll
    for (int f = 0; f < 16; ++f) {
      float4 p0 = *(const float4*)(srow + f * 32 + g * 8);
      float4 p1 = *(const float4*)(srow + f * 32 + g * 8 + 4);
      short8v a;
      a[0] = (short)f2bf(p0.x); a[1] = (short)f2bf(p0.y);
      a[2] = (short)f2bf(p0.z); a[3] = (short)f2bf(p0.w);
      a[4] = (short)f2bf(p1.x); a[5] = (short)f2bf(p1.y);
      a[6] = (short)f2bf(p1.z); a[7] = (short)f2bf(p1.w);
      aF[f] = a;
    }
  }

  for (int h = 0; h < HH; ++h) {
    // ---- P1: hmid = relu(st @ sel_w1[h] + b1), 8 N-tiles per wave ----
    const short* w1h = w1T + h * (HE * SS);
    #pragma unroll
    for (int tl = 0; tl < 8; ++tl) {
      int fb = (nh * 8 + tl) * 16;
      f32x4 acc = {0.f, 0.f, 0.f, 0.f};
      const short* bp = w1h + (size_t)(fb + lr) * SS + g * 8;
      #pragma unroll
      for (int kf = 0; kf < 16; ++kf)
        acc = __builtin_amdgcn_mfma_f32_16x16x32_bf16(
            aF[kf], *(const short8v*)(bp + kf * 32), acc, 0, 0, 0);
      float bias = sel_b1[h * HE + fb + lr];
      #pragma unroll
      for (int r = 0; r < 4; ++r)
        hmid[(mt * 16 + g * 4 + r) * 264 + fb + lr] =
            (short)f2bf(fmaxf(acc[r] + bias, 0.f));
    }
    __syncthreads();
    // ---- P2: sel = hmid @ sel_w2[h], 2 N-tiles per wave, K=256 ----
    #pragma unroll
    for (int tl = 0; tl < 2; ++tl) {
      int eb = (nh * 2 + tl) * 16;
      f32x4 acc = {0.f, 0.f, 0.f, 0.f};
      const short* bp = w2T + (size_t)(h * EE + eb + lr) * HE + g * 8;
      const short* ap = hmid + (mt * 16 + lr) * 264 + g * 8;
      #pragma unroll
      for (int kf = 0; kf < 8; ++kf)
        acc = __builtin_amdgcn_mfma_f32_16x16x32_bf16(
            *(const short8v*)(ap + kf * 32), *(const short8v*)(bp + kf * 32),
            acc, 0, 0, 0);
      #pragma unroll
      for (int r = 0; r < 4; ++r)
        sel[(mt * 16 + g * 4 + r) * 72 + eb + lr] = (short)f2bf(acc[r]);
    }
    __syncthreads();
    // ---- P3: m[:,h,:] = sel @ key_w[h]^T, 2 N-tiles per wave, K=64 ----
    #pragma unroll
    for (int tl = 0; tl < 2; ++tl) {
      int ub = (nh * 2 + tl) * 16;
      f32x4 acc = {0.f, 0.f, 0.f, 0.f};
      const short* bp = kwB + (size_t)(h * UU + ub + lr) * EE + g * 8;
      const short* ap = sel + (mt * 16 + lr) * 72 + g * 8;
      #pragma unroll
      for (int kf = 0; kf < 2; ++kf)
        acc = __builtin_amdgcn_mfma_f32_16x16x32_bf16(
            *(const short8v*)(ap + kf * 32), *(const short8v*)(bp + kf * 32),
            acc, 0, 0, 0);
      #pragma unroll
      for (int r = 0; r < 4; ++r)
        mm[(mt * 16 + g * 4 + r) * 264 + h * 64 + ub + lr] =
            (short)f2bf(acc[r]);
    }
    __syncthreads();   // also guards hmid overwrite by next head's P1
  }

  // ---- P1v: vhid = relu(st @ v_w1 + b1), 2 N-tiles per wave ----
  #pragma unroll
  for (int tl = 0; tl < 2; ++tl) {
    int eb = (nh * 2 + tl) * 16;
    f32x4 acc = {0.f, 0.f, 0.f, 0.f};
    const short* bp = vw1T + (size_t)(eb + lr) * SS + g * 8;
    #pragma unroll
    for (int kf = 0; kf < 16; ++kf)
      acc = __builtin_amdgcn_mfma_f32_16x16x32_bf16(
          aF[kf], *(const short8v*)(bp + kf * 32), acc, 0, 0, 0);
    float bias = v_b1[eb + lr];
    #pragma unroll
    for (int r = 0; r < 4; ++r)
      vhid[(mt * 16 + g * 4 + r) * 72 + eb + lr] =
          (short)f2bf(fmaxf(acc[r] + bias, 0.f));
  }
  __syncthreads();

  // ---- v finalize (reads vhid) + stage st into LDS (writes hmid/sel alias) --
  {
    int b = t >> 3, r = t & 7;
    short8v hv = *(const short8v*)(vhid + b * 72 + r * 8);
    float p = 0.f;
    #pragma unroll
    for (int j = 0; j < 8; ++j) p += bf2f(hv[j]) * v_w2[r * 8 + j];
    p += __shfl_xor(p, 1); p += __shfl_xor(p, 2); p += __shfl_xor(p, 4);
    if (r == 0) out[OUTV + b0 + b] = p + v_b2[0];
  }
  if (w < 2) {                         // waves 0,1 dump A-frags: rows 0..31
    #pragma unroll
    for (int f = 0; f < 16; ++f)
      *(short8v*)(stl + (w * 16 + lr) * 520 + f * 32 + g * 8) = aF[f];
  }
  __syncthreads();

  // ---- P4: logits[b,h,a] = sum_u st[b][a*64+u] * m[b][h*64+u] ----
  #pragma unroll
  for (int i = 0; i < 4; ++i) {
    int o = t + 256 * i;
    int b = o >> 5, hh = (o >> 3) & 3, a = o & 7;
    float lg = 0.f;
    #pragma unroll
    for (int j = 0; j < 8; ++j) {
      short8v s8 = *(const short8v*)(stl + b * 520 + a * 64 + j * 8);
      short8v m8 = *(const short8v*)(mm + b * 264 + hh * 64 + j * 8);
      #pragma unroll
      for (int q = 0; q < 8; ++q) lg += bf2f(s8[q]) * bf2f(m8[q]);
    }
    logitsL[b * 33 + hh * 8 + a] = lg;
  }
  __syncthreads();

  // ---- P5: softmax, entropy, reg ----
  if (t < 128) {
    int b = t >> 2, hh = t & 3;
    float sc[8];
    float rp = 0.f, mx = -1e30f;
    #pragma unroll
    for (int a = 0; a < 8; ++a) {
      float lg = logitsL[b * 33 + hh * 8 + a];
      rp += lg * lg;
      sc[a] = lg * 0.125f;
      mx = fmaxf(mx, sc[a]);
    }
    float sum = 0.f;
    #pragma unroll
    for (int a = 0; a < 8; ++a) { sc[a] = __expf(sc[a] - mx); sum += sc[a]; }
    float inv = 1.f / sum, ent = 0.f;
    #pragma unroll
    for (int a = 0; a < 8; ++a) {
      float wv = sc[a] * inv;
      wtsL[b * 33 + hh * 8 + a] = wv;
      ent += wv * __logf(wv + 1e-8f);
    }
    #pragma unroll
    for (int off = 1; off <= 32; off <<= 1) rp += __shfl_xor(rp, off);
    if ((t & 63) == 0)
      atomicAdd(out + OUTR, rp * (0.001f / ((float)BB * (float)AA)));
    float ep = ent;
    #pragma unroll
    for (int off = 4; off <= 32; off <<= 1) ep += __shfl_xor(ep, off);
    if ((t & 63) < 4) atomicAdd(out + OUTE + hh, -ep / (float)BB);
  }
  __syncthreads();
  {
    int b = t >> 3, a = t & 7;
    out[(size_t)(b0 + b) * AA + a] = wtsL[b * 33 + a] + wtsL[b * 33 + 8 + a] +
                                     wtsL[b * 33 + 16 + a] + wtsL[b * 33 + 24 + a];
  }
}

extern "C" void kernel_launch(void* const* d_in, const int* in_sizes, int n_in,
                              void* d_out, int out_size, void* d_ws, size_t ws_size,
                              hipStream_t stream) {
  (void)in_sizes; (void)n_in; (void)ws_size; (void)out_size;
  const float* states = (const float*)d_in[1];
  const float* sel_w1 = (const float*)d_in[3];
  const float* sel_b1 = (const float*)d_in[4];
  const float* sel_w2 = (const float*)d_in[5];
  const float* key_w  = (const float*)d_in[6];
  const float* v_w1   = (const float*)d_in[7];
  const float* v_b1   = (const float*)d_in[8];
  const float* v_w2   = (const float*)d_in[9];
  const float* v_b2   = (const float*)d_in[10];
  float* out = (float*)d_out;
  unsigned short* ws = (unsigned short*)d_ws;

  hipMemsetAsync(out + OUTR, 0, 5 * sizeof(float), stream);
  prep_kernel<<<(PREP_N + 255) / 256, 256, 0, stream>>>(sel_w1, sel_w2, v_w1,
                                                        key_w, ws);
  qatten_mfma<<<BB / BT, 256, 0, stream>>>(states, sel_b1, v_b1, v_w2, v_b2,
                                           ws, out);
}

// Round 4
// 117.043 us; speedup vs baseline: 3.3064x; 1.5350x over previous
//
#include <hip/hip_runtime.h>
#include <stdint.h>

// Qatten_Weight — Round 4: Round-2 scaffold (known-correct) + two isolated fixes:
//  (1) weights packed into MFMA-frag-contiguous layout (coalesced B-loads)
//  (2) K-outer loops with independent accumulators (MFMA ILP)
// Thread mapping, LDS layout, barriers, epilogue: Round-2 VERBATIM.
// B=16384 A=8 S=512 U=64 H=4 E=64 HE=256; BT=32, grid 512 x 256 threads.

typedef __attribute__((ext_vector_type(8))) short short8v;  // 8 bf16
typedef __attribute__((ext_vector_type(4))) float f32x4;

constexpr int BB = 16384, AA = 8, SS = 512, UU = 64, HH = 4, EE = 64, HE = 256;
constexpr int BT = 32;
constexpr int OUTV = BB * AA, OUTR = OUTV + BB, OUTE = OUTR + 1;

// packed fragment regions in ws (bf16 element offsets); frag = 512 elems = 1KB
constexpr int OFF_W1F  = 0;        // sel_w1: frag = h*256 + ftile*16 + kf   (1024)
constexpr int OFF_W2F  = 524288;   // sel_w2: frag = h*32  + etile*8  + kf   (128)
constexpr int OFF_VW1F = 589824;   // v_w1:   frag = etile*16 + kf           (64)
constexpr int OFF_KWF  = 622592;   // key_w:  frag = h*8 + utile*2 + kf      (32)
constexpr int PREP_N   = 638976;

__device__ __forceinline__ unsigned short f2bf(float x) {
  union { float f; uint32_t u; } v; v.f = x;
  uint32_t r = v.u + 0x7fffu + ((v.u >> 16) & 1u);   // RNE
  return (unsigned short)(r >> 16);
}
__device__ __forceinline__ float bf2f(short h) {
  union { uint32_t u; float f; } v; v.u = ((uint32_t)(unsigned short)h) << 16;
  return v.f;
}

// Pack: within a frag, element r = l*8 + j holds B[k = kf*32 + (l>>4)*8 + j]
// [col = tile*16 + (l&15)] — exactly the 16x16x32 B-fragment lane layout.
__global__ __launch_bounds__(256) void prep_kernel(
    const float* __restrict__ w1, const float* __restrict__ w2,
    const float* __restrict__ vw1, const float* __restrict__ kw,
    unsigned short* __restrict__ ws) {
  int idx = blockIdx.x * 256 + threadIdx.x;
  if (idx >= PREP_N) return;
  int r = idx & 511, l = r >> 3, j = r & 7, lr = l & 15, g = l >> 4;
  int fi = idx >> 9;
  float val;
  if (idx < OFF_W2F) {                    // B[k=s][col=f] for P1
    int h = fi >> 8, tl = (fi >> 4) & 15, kf = fi & 15;
    int s = kf * 32 + g * 8 + j, f = tl * 16 + lr;
    val = w1[((size_t)(h * SS) + s) * HE + f];
  } else if (idx < OFF_VW1F) {            // B[k=f][col=e] for P2
    fi -= OFF_W2F >> 9;
    int h = fi >> 5, tl = (fi >> 3) & 3, kf = fi & 7;
    int k = kf * 32 + g * 8 + j, e = tl * 16 + lr;
    val = w2[((size_t)(h * HE) + k) * EE + e];
  } else if (idx < OFF_KWF) {             // B[k=s][col=e] for P1v
    fi -= OFF_VW1F >> 9;
    int tl = fi >> 4, kf = fi & 15;
    int s = kf * 32 + g * 8 + j, e = tl * 16 + lr;
    val = vw1[(size_t)s * EE + e];
  } else {                                // B[k=e][col=u] for P3
    fi -= OFF_KWF >> 9;
    int h = fi >> 3, tl = (fi >> 1) & 3, kf = fi & 1;
    int k = kf * 32 + g * 8 + j, u = tl * 16 + lr;
    val = kw[((size_t)(h * UU) + u) * EE + k];
  }
  ws[idx] = f2bf(val);
}

__global__ __launch_bounds__(256) void qatten_mfma(
    const float* __restrict__ states, const float* __restrict__ sel_b1,
    const float* __restrict__ v_b1,  const float* __restrict__ v_w2,
    const float* __restrict__ v_b2,  const unsigned short* __restrict__ ws,
    float* __restrict__ out) {
  __shared__ __align__(16) unsigned char lds[63232];
  short* hmid = (short*)lds;                 // [32][264] bf16 (per-head)
  short* sel  = (short*)(lds + 16896);       // [32][72]  bf16 (per-head)
  short* stl  = (short*)lds;                 // [32][520] bf16 (P4 alias)
  short* mm   = (short*)(lds + 33280);       // [32][264] bf16 (all heads)
  short* vhid = (short*)(lds + 50176);       // [32][72]  bf16
  float* logitsL = (float*)(lds + 54784);    // [32][33]
  float* wtsL    = (float*)(lds + 59008);    // [32][33]

  const int t  = threadIdx.x;
  const int w  = t >> 6, l = t & 63;
  const int mt = w & 1, nh = w >> 1;         // M-tile, N-half (Round-2 mapping)
  const int lr = l & 15, g = l >> 4;
  const int b0 = blockIdx.x * BT;
  const short* w1f  = (const short*)ws + OFF_W1F;
  const short* w2f  = (const short*)ws + OFF_W2F;
  const short* vw1f = (const short*)ws + OFF_VW1F;
  const short* kwf  = (const short*)ws + OFF_KWF;

  // ---- A-fragments: 16 rows of st, bf16, in registers (Round-2 verbatim) ----
  short8v aF[16];
  {
    const float* srow = states + (size_t)(b0 + mt * 16 + lr) * (AA * SS);
    #pragma unroll
    for (int f = 0; f < 16; ++f) {
      float4 p0 = *(const float4*)(srow + f * 32 + g * 8);
      float4 p1 = *(const float4*)(srow + f * 32 + g * 8 + 4);
      short8v a;
      a[0] = (short)f2bf(p0.x); a[1] = (short)f2bf(p0.y);
      a[2] = (short)f2bf(p0.z); a[3] = (short)f2bf(p0.w);
      a[4] = (short)f2bf(p1.x); a[5] = (short)f2bf(p1.y);
      a[6] = (short)f2bf(p1.z); a[7] = (short)f2bf(p1.w);
      aF[f] = a;
    }
  }

  for (int h = 0; h < HH; ++h) {
    // ---- P1: hmid = relu(st @ sel_w1[h] + b1); K-outer, 8 indep accs ----
    f32x4 acc[8] = {{0,0,0,0},{0,0,0,0},{0,0,0,0},{0,0,0,0},
                    {0,0,0,0},{0,0,0,0},{0,0,0,0},{0,0,0,0}};
    {
      const short* bb = w1f + ((size_t)(h * 256 + nh * 128)) * 512 + l * 8;
      #pragma unroll
      for (int kf = 0; kf < 16; ++kf) {
        short8v af = aF[kf];
        #pragma unroll
        for (int tl = 0; tl < 8; ++tl)
          acc[tl] = __builtin_amdgcn_mfma_f32_16x16x32_bf16(
              af, *(const short8v*)(bb + (size_t)(tl * 16 + kf) * 512),
              acc[tl], 0, 0, 0);
      }
    }
    #pragma unroll
    for (int tl = 0; tl < 8; ++tl) {
      int fb = (nh * 8 + tl) * 16;
      float bias = sel_b1[h * HE + fb + lr];
      #pragma unroll
      for (int r2 = 0; r2 < 4; ++r2)
        hmid[(mt * 16 + g * 4 + r2) * 264 + fb + lr] =
            (short)f2bf(fmaxf(acc[tl][r2] + bias, 0.f));
    }
    __syncthreads();

    // ---- P2: sel = hmid @ sel_w2[h]; K-outer, 2 indep accs, K=256 ----
    f32x4 a2[2] = {{0,0,0,0},{0,0,0,0}};
    {
      const short* ah = hmid + (mt * 16 + lr) * 264 + g * 8;
      const short* b2 = w2f + ((size_t)(h * 32 + nh * 16)) * 512 + l * 8;
      #pragma unroll
      for (int kf = 0; kf < 8; ++kf) {
        short8v af = *(const short8v*)(ah + kf * 32);
        #pragma unroll
        for (int tl = 0; tl < 2; ++tl)
          a2[tl] = __builtin_amdgcn_mfma_f32_16x16x32_bf16(
              af, *(const short8v*)(b2 + (size_t)(tl * 8 + kf) * 512),
              a2[tl], 0, 0, 0);
      }
    }
    #pragma unroll
    for (int tl = 0; tl < 2; ++tl)
      #pragma unroll
      for (int r2 = 0; r2 < 4; ++r2)
        sel[(mt * 16 + g * 4 + r2) * 72 + (nh * 2 + tl) * 16 + lr] =
            (short)f2bf(a2[tl][r2]);
    __syncthreads();

    // ---- P3: m = sel @ key_w[h]^T; K-outer, 2 indep accs, K=64 ----
    f32x4 a3[2] = {{0,0,0,0},{0,0,0,0}};
    {
      const short* as = sel + (mt * 16 + lr) * 72 + g * 8;
      const short* b3 = kwf + ((size_t)(h * 8 + nh * 4)) * 512 + l * 8;
      #pragma unroll
      for (int kf = 0; kf < 2; ++kf) {
        short8v af = *(const short8v*)(as + kf * 32);
        #pragma unroll
        for (int tl = 0; tl < 2; ++tl)
          a3[tl] = __builtin_amdgcn_mfma_f32_16x16x32_bf16(
              af, *(const short8v*)(b3 + (size_t)(tl * 2 + kf) * 512),
              a3[tl], 0, 0, 0);
      }
    }
    #pragma unroll
    for (int tl = 0; tl < 2; ++tl)
      #pragma unroll
      for (int r2 = 0; r2 < 4; ++r2)
        mm[(mt * 16 + g * 4 + r2) * 264 + h * 64 + (nh * 2 + tl) * 16 + lr] =
            (short)f2bf(a3[tl][r2]);
    __syncthreads();   // also guards hmid overwrite by next head's P1
  }

  // ---- P1v: vhid = relu(st @ v_w1 + b1); K-outer, 2 indep accs ----
  {
    f32x4 av[2] = {{0,0,0,0},{0,0,0,0}};
    const short* bv = vw1f + ((size_t)(nh * 32)) * 512 + l * 8;
    #pragma unroll
    for (int kf = 0; kf < 16; ++kf) {
      short8v af = aF[kf];
      #pragma unroll
      for (int tl = 0; tl < 2; ++tl)
        av[tl] = __builtin_amdgcn_mfma_f32_16x16x32_bf16(
            af, *(const short8v*)(bv + (size_t)(tl * 16 + kf) * 512),
            av[tl], 0, 0, 0);
    }
    #pragma unroll
    for (int tl = 0; tl < 2; ++tl) {
      int eb = (nh * 2 + tl) * 16;
      float bias = v_b1[eb + lr];
      #pragma unroll
      for (int r2 = 0; r2 < 4; ++r2)
        vhid[(mt * 16 + g * 4 + r2) * 72 + eb + lr] =
            (short)f2bf(fmaxf(av[tl][r2] + bias, 0.f));
    }
  }
  __syncthreads();

  // ---- v finalize (reads vhid) + stage st into LDS (Round-2 verbatim) ----
  {
    int b = t >> 3, r = t & 7;
    short8v hv = *(const short8v*)(vhid + b * 72 + r * 8);
    float p = 0.f;
    #pragma unroll
    for (int j = 0; j < 8; ++j) p += bf2f(hv[j]) * v_w2[r * 8 + j];
    p += __shfl_xor(p, 1); p += __shfl_xor(p, 2); p += __shfl_xor(p, 4);
    if (r == 0) out[OUTV + b0 + b] = p + v_b2[0];
  }
  if (w < 2) {                         // waves 0,1 dump A-frags: rows 0..31
    #pragma unroll
    for (int f = 0; f < 16; ++f)
      *(short8v*)(stl + (w * 16 + lr) * 520 + f * 32 + g * 8) = aF[f];
  }
  __syncthreads();

  // ---- P4: logits[b,h,a] = sum_u st[b][a*64+u] * m[b][h*64+u] ----
  #pragma unroll
  for (int i = 0; i < 4; ++i) {
    int o = t + 256 * i;
    int b = o >> 5, hh = (o >> 3) & 3, a = o & 7;
    float lg = 0.f;
    #pragma unroll
    for (int j = 0; j < 8; ++j) {
      short8v s8 = *(const short8v*)(stl + b * 520 + a * 64 + j * 8);
      short8v m8 = *(const short8v*)(mm + b * 264 + hh * 64 + j * 8);
      #pragma unroll
      for (int q = 0; q < 8; ++q) lg += bf2f(s8[q]) * bf2f(m8[q]);
    }
    logitsL[b * 33 + hh * 8 + a] = lg;
  }
  __syncthreads();

  // ---- P5: softmax, entropy, reg (Round-2 verbatim) ----
  if (t < 128) {
    int b = t >> 2, hh = t & 3;
    float sc[8];
    float rp = 0.f, mx = -1e30f;
    #pragma unroll
    for (int a = 0; a < 8; ++a) {
      float lg = logitsL[b * 33 + hh * 8 + a];
      rp += lg * lg;
      sc[a] = lg * 0.125f;
      mx = fmaxf(mx, sc[a]);
    }
    float sum = 0.f;
    #pragma unroll
    for (int a = 0; a < 8; ++a) { sc[a] = __expf(sc[a] - mx); sum += sc[a]; }
    float inv = 1.f / sum, ent = 0.f;
    #pragma unroll
    for (int a = 0; a < 8; ++a) {
      float wv = sc[a] * inv;
      wtsL[b * 33 + hh * 8 + a] = wv;
      ent += wv * __logf(wv + 1e-8f);
    }
    #pragma unroll
    for (int off = 1; off <= 32; off <<= 1) rp += __shfl_xor(rp, off);
    if ((t & 63) == 0)
      atomicAdd(out + OUTR, rp * (0.001f / ((float)BB * (float)AA)));
    float ep = ent;
    #pragma unroll
    for (int off = 4; off <= 32; off <<= 1) ep += __shfl_xor(ep, off);
    if ((t & 63) < 4) atomicAdd(out + OUTE + hh, -ep / (float)BB);
  }
  __syncthreads();
  {
    int b = t >> 3, a = t & 7;
    out[(size_t)(b0 + b) * AA + a] = wtsL[b * 33 + a] + wtsL[b * 33 + 8 + a] +
                                     wtsL[b * 33 + 16 + a] + wtsL[b * 33 + 24 + a];
  }
}

extern "C" void kernel_launch(void* const* d_in, const int* in_sizes, int n_in,
                              void* d_out, int out_size, void* d_ws, size_t ws_size,
                              hipStream_t stream) {
  (void)in_sizes; (void)n_in; (void)ws_size; (void)out_size;
  const float* states = (const float*)d_in[1];
  const float* sel_w1 = (const float*)d_in[3];
  const float* sel_b1 = (const float*)d_in[4];
  const float* sel_w2 = (const float*)d_in[5];
  const float* key_w  = (const float*)d_in[6];
  const float* v_w1   = (const float*)d_in[7];
  const float* v_b1   = (const float*)d_in[8];
  const float* v_w2   = (const float*)d_in[9];
  const float* v_b2   = (const float*)d_in[10];
  float* out = (float*)d_out;
  unsigned short* ws = (unsigned short*)d_ws;

  hipMemsetAsync(out + OUTR, 0, 5 * sizeof(float), stream);
  prep_kernel<<<(PREP_N + 255) / 256, 256, 0, stream>>>(sel_w1, sel_w2, v_w1,
                                                        key_w, ws);
  qatten_mfma<<<BB / BT, 256, 0, stream>>>(states, sel_b1, v_b1, v_w2, v_b2,
                                           ws, out);
}